// Round 1
// baseline (206.062 us; speedup 1.0000x reference)
//
#include <hip/hip_runtime.h>
#include <hip/hip_bf16.h>
#include <math.h>

#define BB 1024
#define DD 64
#define HH 128

typedef __bf16 bf16x8 __attribute__((ext_vector_type(8)));
typedef float floatx4 __attribute__((ext_vector_type(4)));

__device__ __forceinline__ unsigned short f2bf(float v) {
    union { float f; unsigned u; } a; a.f = v;
    unsigned r = a.u + 0x7fffu + ((a.u >> 16) & 1u);
    return (unsigned short)(r >> 16);
}

// ---------------------------------------------------------------------------
// Prep: c1[i,h] = x_i @ (Wi+Wd) + b1 ; c2T[h,j] = x_j @ (Wj-Wd) ;
//       wpack = Wab in per-lane bf16 MFMA B-fragment order.
// ---------------------------------------------------------------------------
__global__ __launch_bounds__(256) void prep_kernel(
    const float* __restrict__ x, const float* __restrict__ W1,
    const float* __restrict__ b1,
    float* __restrict__ c1, float* __restrict__ c2T,
    unsigned short* __restrict__ wpack)
{
    __shared__ float WA[DD][HH];
    __shared__ float WBm[DD][HH];
    __shared__ float xr[16][DD];
    const int t = threadIdx.x;
    for (int f = t; f < DD * HH; f += 256) {
        int k = f >> 7, h = f & 127;
        float wi = W1[k * HH + h];
        float wj = W1[(DD + k) * HH + h];
        float wd = W1[(2 * DD + k) * HH + h];
        WA[k][h] = wi + wd;
        WBm[k][h] = wj - wd;
    }
    const int i0 = blockIdx.x * 16;
    for (int f = t; f < 16 * DD; f += 256)
        xr[f >> 6][f & 63] = x[(i0 + (f >> 6)) * DD + (f & 63)];
    __syncthreads();

    const int half = t >> 7;
    const int h = t & 127;
    for (int it = 0; it < 16; ++it) {
        int i = i0 + it;
        float acc = 0.f;
        if (half == 0) {
            #pragma unroll 8
            for (int k = 0; k < DD; k++) acc += xr[it][k] * WA[k][h];
            c1[i * HH + h] = acc + b1[h];
        } else {
            #pragma unroll 8
            for (int k = 0; k < DD; k++) acc += xr[it][k] * WBm[k][h];
            c2T[h * BB + i] = acc;
        }
    }
    if (blockIdx.x == 0) {
        // wpack[((t8*2+s)*64 + lane)*8 + jj] = bf16(Wab[s*32 + (lane>>4)*8 + jj][t8*16 + (lane&15)])
        for (int f = t; f < 16384; f += 256) {
            int jj = f & 7, l = (f >> 3) & 63, u = f >> 9;
            int s = u & 1, t8 = u >> 1;
            int k = s * 32 + ((l >> 4) << 3) + jj;
            int hh = t8 * 16 + (l & 15);
            wpack[f] = f2bf(W1[(3 * DD + k) * HH + hh]);
        }
    }
}

// ---------------------------------------------------------------------------
// Pair kernel: S[q][i][h] = sum_{j in quarter q} relu(|x_i-x_j|@Wab + c1[i]+c2[j])
// Block = 4 waves = 4 consecutive i, one j-quarter (256 j = 16 tiles of 16).
// MFMA 16x16x32 bf16: M=16 j-rows, N=16 h (8 n-tiles), K=64 (2 halves).
// ---------------------------------------------------------------------------
__global__ __launch_bounds__(256) void pair_kernel(
    const float* __restrict__ x, const float* __restrict__ c1,
    const float* __restrict__ c2T, const unsigned short* __restrict__ wpack,
    float* __restrict__ Sp)
{
    const int wave = threadIdx.x >> 6;
    const int l = threadIdx.x & 63;
    const int quad = l >> 4, lm = l & 15;
    const int ig = blockIdx.x >> 2;
    const int jq = blockIdx.x & 3;
    const int i = ig * 4 + wave;
    const int dbase = quad * 8;

    // x_i slice for this lane's k positions (k = quad*8 + jj + 32*s)
    float xi[16];
    {
        const float* xr = x + i * DD + dbase;
        *(float4*)(xi)      = *(const float4*)(xr);
        *(float4*)(xi + 4)  = *(const float4*)(xr + 4);
        *(float4*)(xi + 8)  = *(const float4*)(xr + 32);
        *(float4*)(xi + 12) = *(const float4*)(xr + 36);
    }
    float c1r[8];
    #pragma unroll
    for (int t = 0; t < 8; t++) c1r[t] = c1[i * HH + t * 16 + lm];

    bf16x8 wf[16];
    #pragma unroll
    for (int u = 0; u < 16; u++)
        wf[u] = *(const bf16x8*)(wpack + (u * 64 + l) * 8);

    float S[8];
    #pragma unroll
    for (int t = 0; t < 8; t++) S[t] = 0.f;

    const int j0base = jq * 256;
    for (int tile = 0; tile < 16; ++tile) {
        const int j0 = j0base + tile * 16;
        float xj[16];
        {
            const float* xr = x + (j0 + lm) * DD + dbase;
            *(float4*)(xj)      = *(const float4*)(xr);
            *(float4*)(xj + 4)  = *(const float4*)(xr + 4);
            *(float4*)(xj + 8)  = *(const float4*)(xr + 32);
            *(float4*)(xj + 12) = *(const float4*)(xr + 36);
        }
        bf16x8 af0, af1;
        #pragma unroll
        for (int jj = 0; jj < 8; jj++) {
            af0[jj] = (__bf16)fabsf(xi[jj] - xj[jj]);
            af1[jj] = (__bf16)fabsf(xi[8 + jj] - xj[8 + jj]);
        }
        floatx4 acc[8];
        #pragma unroll
        for (int t = 0; t < 8; t++) {
            // C[m=quad*4+r][n=lm+16t] init = c2[j0+quad*4+r][h] + c1[i][h]
            float4 c2v = *(const float4*)(c2T + (t * 16 + lm) * BB + j0 + quad * 4);
            acc[t][0] = c2v.x + c1r[t];
            acc[t][1] = c2v.y + c1r[t];
            acc[t][2] = c2v.z + c1r[t];
            acc[t][3] = c2v.w + c1r[t];
        }
        #pragma unroll
        for (int t = 0; t < 8; t++) {
            acc[t] = __builtin_amdgcn_mfma_f32_16x16x32_bf16(af0, wf[t * 2 + 0], acc[t], 0, 0, 0);
            acc[t] = __builtin_amdgcn_mfma_f32_16x16x32_bf16(af1, wf[t * 2 + 1], acc[t], 0, 0, 0);
        }
        #pragma unroll
        for (int t = 0; t < 8; t++) {
            S[t] += fmaxf(acc[t][0], 0.f);
            S[t] += fmaxf(acc[t][1], 0.f);
            S[t] += fmaxf(acc[t][2], 0.f);
            S[t] += fmaxf(acc[t][3], 0.f);
        }
    }
    // reduce across the 4 quads (same h = lm + 16t, different j-rows)
    #pragma unroll
    for (int t = 0; t < 8; t++) {
        S[t] += __shfl_xor(S[t], 16, 64);
        S[t] += __shfl_xor(S[t], 32, 64);
    }
    if (quad == 0) {
        #pragma unroll
        for (int t = 0; t < 8; t++)
            Sp[(jq * BB + i) * HH + t * 16 + lm] = S[t];
    }
}

// ---------------------------------------------------------------------------
// Head: m[i,h'] = ( b2[h'] + sum_k (S[i,k]/B) * W2[k,h'] ) / tau_i
// Block = 2 i x 128 h'.
// ---------------------------------------------------------------------------
__global__ __launch_bounds__(256) void head_kernel(
    const float* __restrict__ Sp, const float* __restrict__ W2,
    const float* __restrict__ b2, const float* __restrict__ x,
    const float* __restrict__ Wt, const float* __restrict__ bt,
    float* __restrict__ m)
{
    __shared__ float Srow[2][HH];
    __shared__ float taus[2];
    const int t = threadIdx.x;
    const int ii = t >> 7, h = t & 127;
    const int i0 = blockIdx.x * 2;
    const int i = i0 + ii;

    float s = 0.f;
    #pragma unroll
    for (int q = 0; q < 4; q++) s += Sp[(q * BB + i) * HH + h];
    Srow[ii][h] = s * (1.0f / (float)BB);

    if ((t & 127) < 64) {
        int lane = t & 63;
        float p = x[i * DD + lane] * Wt[lane];
        #pragma unroll
        for (int off = 32; off; off >>= 1) p += __shfl_down(p, off, 64);
        if (lane == 0) {
            float z = p + bt[0];
            float sp = (z > 20.f) ? z : log1pf(expf(z));
            taus[ii] = fmaxf(sp, 0.01f) + 1.0f;
        }
    }
    __syncthreads();
    float acc = b2[h];
    #pragma unroll 8
    for (int k = 0; k < HH; k++) acc += Srow[ii][k] * W2[k * HH + h];
    m[i * HH + h] = acc / taus[ii];
}

// ---------------------------------------------------------------------------
// Tail: h = relu(m@Wa+ba); y = h + x@Wr + br; out = LayerNorm(y)*gamma+beta
// Block = 2 i x 128 h'.
// ---------------------------------------------------------------------------
__global__ __launch_bounds__(256) void tail_kernel(
    const float* __restrict__ m, const float* __restrict__ Wa,
    const float* __restrict__ ba, const float* __restrict__ x,
    const float* __restrict__ Wr, const float* __restrict__ br,
    const float* __restrict__ gamma, const float* __restrict__ beta,
    float* __restrict__ out)
{
    __shared__ float mrow[2][HH];
    __shared__ float xrow[2][DD];
    __shared__ float red1[2][2];
    __shared__ float red2[2][2];
    const int t = threadIdx.x;
    const int ii = t >> 7, h = t & 127;
    const int i0 = blockIdx.x * 2;
    const int i = i0 + ii;

    mrow[ii][h] = m[i * HH + h];
    if (h < 64) xrow[ii][h] = x[i * DD + h];
    __syncthreads();

    float acc = ba[h];
    #pragma unroll 8
    for (int k = 0; k < HH; k++) acc += mrow[ii][k] * Wa[k * HH + h];
    float hv = fmaxf(acc, 0.f);
    float y = hv + br[h];
    #pragma unroll 8
    for (int d = 0; d < DD; d++) y += xrow[ii][d] * Wr[d * HH + h];

    const int wv = (t >> 6) & 1;
    const int lane = t & 63;
    float p = y;
    #pragma unroll
    for (int off = 32; off; off >>= 1) p += __shfl_down(p, off, 64);
    if (lane == 0) red1[ii][wv] = p;
    __syncthreads();
    float mu = (red1[ii][0] + red1[ii][1]) * (1.f / (float)HH);
    float dy = y - mu;
    float q = dy * dy;
    #pragma unroll
    for (int off = 32; off; off >>= 1) q += __shfl_down(q, off, 64);
    if (lane == 0) red2[ii][wv] = q;
    __syncthreads();
    float var = (red2[ii][0] + red2[ii][1]) * (1.f / (float)HH);
    out[i * HH + h] = dy * rsqrtf(var + 1e-5f) * gamma[h] + beta[h];
}

// ---------------------------------------------------------------------------
extern "C" void kernel_launch(void* const* d_in, const int* in_sizes, int n_in,
                              void* d_out, int out_size, void* d_ws, size_t ws_size,
                              hipStream_t stream)
{
    const float* x     = (const float*)d_in[0];
    const float* W1    = (const float*)d_in[1];
    const float* b1    = (const float*)d_in[2];
    const float* W2    = (const float*)d_in[3];
    const float* b2    = (const float*)d_in[4];
    const float* Wt    = (const float*)d_in[5];
    const float* bt    = (const float*)d_in[6];
    const float* Wa    = (const float*)d_in[7];
    const float* ba    = (const float*)d_in[8];
    const float* Wr    = (const float*)d_in[9];
    const float* br    = (const float*)d_in[10];
    const float* gamma = (const float*)d_in[11];
    const float* beta  = (const float*)d_in[12];
    float* out = (float*)d_out;

    char* ws = (char*)d_ws;
    float*          c1    = (float*)(ws);                       // 512 KB
    float*          c2T   = (float*)(ws + (512 << 10));         // 512 KB
    unsigned short* wpack = (unsigned short*)(ws + (1024 << 10)); // 32 KB
    float*          Sp    = (float*)(ws + (1056 << 10));        // 2 MB
    float*          mbuf  = (float*)(ws + (3104 << 10));        // 512 KB

    prep_kernel<<<64, 256, 0, stream>>>(x, W1, b1, c1, c2T, wpack);
    pair_kernel<<<1024, 256, 0, stream>>>(x, c1, c2T, wpack, Sp);
    head_kernel<<<BB / 2, 256, 0, stream>>>(Sp, W2, b2, x, Wt, bt, mbuf);
    tail_kernel<<<BB / 2, 256, 0, stream>>>(mbuf, Wa, ba, x, Wr, br, gamma, beta, out);
}

// Round 2
// 146.433 us; speedup vs baseline: 1.4072x; 1.4072x over previous
//
#include <hip/hip_runtime.h>
#include <hip/hip_bf16.h>
#include <math.h>

#define BB 1024
#define DD 64
#define HH 128

typedef __bf16 bf16x8 __attribute__((ext_vector_type(8)));
typedef float floatx4 __attribute__((ext_vector_type(4)));

__device__ __forceinline__ unsigned short f2bf(float v) {
    union { float f; unsigned u; } a; a.f = v;
    unsigned r = a.u + 0x7fffu + ((a.u >> 16) & 1u);
    return (unsigned short)(r >> 16);
}

// async global -> LDS, 16B per lane. lds_wave_base must be wave-uniform;
// HW adds lane*16.
__device__ __forceinline__ void async_cp16(const float* g, float* lds_wave_base) {
    __builtin_amdgcn_global_load_lds(
        (const __attribute__((address_space(1))) unsigned int*)g,
        (__attribute__((address_space(3))) unsigned int*)lds_wave_base,
        16, 0, 0);
}

// ---------------------------------------------------------------------------
// Prep: c1[i,h] = x_i @ (Wi+Wd) + b1 ;
//       c2P = x_j @ (Wj-Wd) pre-permuted into MFMA C-fragment order:
//         c2P[(j>>4)*2048 + (h>>4)*256 + (((j&15)>>2)*16 + (h&15))*4 + (j&3)]
//       wpack = Wab in per-lane bf16 MFMA B-fragment order.
// Grid 512 blocks x 256 thr; block = 2 i rows x 128 h.
// ---------------------------------------------------------------------------
__global__ __launch_bounds__(256) void prep_kernel(
    const float* __restrict__ x, const float* __restrict__ W1,
    const float* __restrict__ b1,
    float* __restrict__ c1, float* __restrict__ c2P,
    unsigned short* __restrict__ wpack)
{
    __shared__ float xr[2][DD];
    const int t = threadIdx.x;
    const int i0 = blockIdx.x * 2;
    if (t < 2 * DD) xr[t >> 6][t & 63] = x[i0 * DD + t];
    __syncthreads();

    const int ii = t >> 7, h = t & 127;
    const int i = i0 + ii;
    float a1 = 0.f, a2 = 0.f;
    #pragma unroll 16
    for (int k = 0; k < DD; k++) {
        float wi = W1[k * HH + h];
        float wj = W1[(DD + k) * HH + h];
        float wd = W1[(2 * DD + k) * HH + h];
        float xv = xr[ii][k];
        a1 = fmaf(xv, wi + wd, a1);
        a2 = fmaf(xv, wj - wd, a2);
    }
    c1[i * HH + h] = a1 + b1[h];
    const int jl = i & 15;
    c2P[(i >> 4) * 2048 + (h >> 4) * 256 + (((jl >> 2) << 4) | (h & 15)) * 4 + (jl & 3)] = a2;

    if (blockIdx.x == 0) {
        // wpack[((t8*2+s)*64 + lane)*8 + jj] = bf16(Wab[s*32+(lane>>4)*8+jj][t8*16+(lane&15)])
        for (int f = t; f < 16384; f += 256) {
            int jj = f & 7, l = (f >> 3) & 63, u = f >> 9;
            int s = u & 1, t8 = u >> 1;
            int k = s * 32 + ((l >> 4) << 3) + jj;
            int hh = t8 * 16 + (l & 15);
            wpack[f] = f2bf(W1[(3 * DD + k) * HH + hh]);
        }
    }
}

// ---------------------------------------------------------------------------
// Pair kernel: Sp[jq][i][h] = sum_{j in quarter jq} relu(|x_i-x_j|@Wab + c1[i]+c2[j])
// Block = 4 waves = 4 consecutive i, one j-quarter (256 j = 16 tiles of 16).
// Per-tile xj (4 KB) + c2 fragment tile (8 KB) staged async into LDS,
// double-buffered; prefetch of tile t+1 overlaps compute of tile t.
// ---------------------------------------------------------------------------
__global__ __launch_bounds__(256) void pair_kernel(
    const float* __restrict__ x, const float* __restrict__ c1,
    const float* __restrict__ c2P, const unsigned short* __restrict__ wpack,
    float* __restrict__ Sp)
{
    __shared__ __align__(16) float xs[2][16][DD];   // 8 KB
    __shared__ __align__(16) float c2s[2][2048];    // 16 KB

    const int t = threadIdx.x;
    const int wave = t >> 6;
    const int l = t & 63;
    const int quad = l >> 4, lm = l & 15;
    const int ig = blockIdx.x >> 2;
    const int jq = blockIdx.x & 3;
    const int i = ig * 4 + wave;
    const int j0base = jq * 256;

    // stage tile 0 (async)
    {
        async_cp16(x + (j0base + (t >> 4)) * DD + (t & 15) * 4,
                   &xs[0][0][0] + wave * 256);
        const float* cg = c2P + (j0base >> 4) * 2048;
        async_cp16(cg + t * 4,        &c2s[0][0]    + wave * 256);
        async_cp16(cg + 1024 + t * 4, &c2s[0][1024] + wave * 256);
    }

    // wave-private register data (overlaps with staging)
    float xi[16];
    {
        const float* xrg = x + i * DD + quad * 8;
        *(float4*)(xi)      = *(const float4*)(xrg);
        *(float4*)(xi + 4)  = *(const float4*)(xrg + 4);
        *(float4*)(xi + 8)  = *(const float4*)(xrg + 32);
        *(float4*)(xi + 12) = *(const float4*)(xrg + 36);
    }
    float c1r[8];
    #pragma unroll
    for (int t8 = 0; t8 < 8; t8++) c1r[t8] = c1[i * HH + t8 * 16 + lm];
    bf16x8 wf[16];
    #pragma unroll
    for (int u = 0; u < 16; u++)
        wf[u] = *(const bf16x8*)(wpack + (u * 64 + l) * 8);

    float S[8];
    #pragma unroll
    for (int t8 = 0; t8 < 8; t8++) S[t8] = 0.f;

    for (int tile = 0; tile < 16; ++tile) {
        const int cur = tile & 1;
        __syncthreads();   // tile's staged data landed; prev buffer free

        if (tile < 15) {   // prefetch tile+1 into other buffer (async)
            const int jn = j0base + (tile + 1) * 16;
            const int nb = cur ^ 1;
            async_cp16(x + (jn + (t >> 4)) * DD + (t & 15) * 4,
                       &xs[nb][0][0] + wave * 256);
            const float* cg = c2P + (jn >> 4) * 2048;
            async_cp16(cg + t * 4,        &c2s[nb][0]    + wave * 256);
            async_cp16(cg + 1024 + t * 4, &c2s[nb][1024] + wave * 256);
        }

        // A fragment: |x_i - x_j|, rows j = lm, cols k = quad*8+jj (+32)
        const float* xrow = &xs[cur][lm][quad * 8];
        float4 a0 = *(const float4*)(xrow);
        float4 a1 = *(const float4*)(xrow + 4);
        float4 a2 = *(const float4*)(xrow + 32);
        float4 a3 = *(const float4*)(xrow + 36);
        bf16x8 af0, af1;
        af0[0] = (__bf16)fabsf(xi[0] - a0.x);  af0[1] = (__bf16)fabsf(xi[1] - a0.y);
        af0[2] = (__bf16)fabsf(xi[2] - a0.z);  af0[3] = (__bf16)fabsf(xi[3] - a0.w);
        af0[4] = (__bf16)fabsf(xi[4] - a1.x);  af0[5] = (__bf16)fabsf(xi[5] - a1.y);
        af0[6] = (__bf16)fabsf(xi[6] - a1.z);  af0[7] = (__bf16)fabsf(xi[7] - a1.w);
        af1[0] = (__bf16)fabsf(xi[8] - a2.x);  af1[1] = (__bf16)fabsf(xi[9] - a2.y);
        af1[2] = (__bf16)fabsf(xi[10] - a2.z); af1[3] = (__bf16)fabsf(xi[11] - a2.w);
        af1[4] = (__bf16)fabsf(xi[12] - a3.x); af1[5] = (__bf16)fabsf(xi[13] - a3.y);
        af1[6] = (__bf16)fabsf(xi[14] - a3.z); af1[7] = (__bf16)fabsf(xi[15] - a3.w);

        floatx4 acc[8];
        #pragma unroll
        for (int t8 = 0; t8 < 8; t8++) {
            acc[t8][0] = c1r[t8]; acc[t8][1] = c1r[t8];
            acc[t8][2] = c1r[t8]; acc[t8][3] = c1r[t8];
        }
        #pragma unroll
        for (int t8 = 0; t8 < 8; t8++) {
            acc[t8] = __builtin_amdgcn_mfma_f32_16x16x32_bf16(af0, wf[t8 * 2 + 0], acc[t8], 0, 0, 0);
            acc[t8] = __builtin_amdgcn_mfma_f32_16x16x32_bf16(af1, wf[t8 * 2 + 1], acc[t8], 0, 0, 0);
        }
        // epilogue: + c2 (fragment-ordered, sequential b128 from LDS), relu, sum over j
        #pragma unroll
        for (int t8 = 0; t8 < 8; t8++) {
            float4 c2v = *(const float4*)(&c2s[cur][t8 * 256 + l * 4]);
            S[t8] += fmaxf(acc[t8][0] + c2v.x, 0.f);
            S[t8] += fmaxf(acc[t8][1] + c2v.y, 0.f);
            S[t8] += fmaxf(acc[t8][2] + c2v.z, 0.f);
            S[t8] += fmaxf(acc[t8][3] + c2v.w, 0.f);
        }
    }

    // reduce across the 4 quads (same h = lm + 16*t8, different j-rows)
    #pragma unroll
    for (int t8 = 0; t8 < 8; t8++) {
        S[t8] += __shfl_xor(S[t8], 16, 64);
        S[t8] += __shfl_xor(S[t8], 32, 64);
    }
    if (quad == 0) {
        #pragma unroll
        for (int t8 = 0; t8 < 8; t8++)
            Sp[(jq * BB + i) * HH + t8 * 16 + lm] = S[t8];
    }
}

// ---------------------------------------------------------------------------
// Finish (head+tail merged): per row i
//   m = (b2 + (mean_j S)/tau @ W2) ; h = relu(m@Wa+ba); y = h + x@Wr + br;
//   out = LayerNorm(y)*gamma+beta.  Block = 2 i x 128 h.
// ---------------------------------------------------------------------------
__global__ __launch_bounds__(256) void finish_kernel(
    const float* __restrict__ Sp, const float* __restrict__ W2,
    const float* __restrict__ b2, const float* __restrict__ x,
    const float* __restrict__ Wt, const float* __restrict__ bt,
    const float* __restrict__ Wa, const float* __restrict__ ba,
    const float* __restrict__ Wr, const float* __restrict__ br,
    const float* __restrict__ gamma, const float* __restrict__ beta,
    float* __restrict__ out)
{
    __shared__ float Srow[2][HH];
    __shared__ float mrow[2][HH];
    __shared__ float xrow[2][DD];
    __shared__ float taus[2];
    __shared__ float red1[2][2];
    __shared__ float red2[2][2];
    const int t = threadIdx.x;
    const int ii = t >> 7, h = t & 127;
    const int i = blockIdx.x * 2 + ii;

    float s = 0.f;
    #pragma unroll
    for (int q = 0; q < 4; q++) s += Sp[(q * BB + i) * HH + h];
    Srow[ii][h] = s * (1.0f / (float)BB);
    if (h < 64) xrow[ii][h] = x[i * DD + h];

    if ((t & 127) < 64) {
        int lane = t & 63;
        float p = x[i * DD + lane] * Wt[lane];
        #pragma unroll
        for (int off = 32; off; off >>= 1) p += __shfl_down(p, off, 64);
        if (lane == 0) {
            float z = p + bt[0];
            float sp = (z > 20.f) ? z : log1pf(expf(z));
            taus[ii] = fmaxf(sp, 0.01f) + 1.0f;
        }
    }
    __syncthreads();

    float acc = b2[h];
    #pragma unroll 8
    for (int k = 0; k < HH; k++) acc += Srow[ii][k] * W2[k * HH + h];
    float mv = acc / taus[ii];
    mrow[ii][h] = mv;
    __syncthreads();

    float acc2 = ba[h];
    #pragma unroll 8
    for (int k = 0; k < HH; k++) acc2 += mrow[ii][k] * Wa[k * HH + h];
    float y = fmaxf(acc2, 0.f) + br[h];
    #pragma unroll 8
    for (int d = 0; d < DD; d++) y += xrow[ii][d] * Wr[d * HH + h];

    const int wv = (t >> 6) & 1;
    const int lane = t & 63;
    float p = y;
    #pragma unroll
    for (int off = 32; off; off >>= 1) p += __shfl_down(p, off, 64);
    if (lane == 0) red1[ii][wv] = p;
    __syncthreads();
    float mu = (red1[ii][0] + red1[ii][1]) * (1.f / (float)HH);
    float dy = y - mu;
    float q = dy * dy;
    #pragma unroll
    for (int off = 32; off; off >>= 1) q += __shfl_down(q, off, 64);
    if (lane == 0) red2[ii][wv] = q;
    __syncthreads();
    float var = (red2[ii][0] + red2[ii][1]) * (1.f / (float)HH);
    out[i * HH + h] = dy * rsqrtf(var + 1e-5f) * gamma[h] + beta[h];
}

// ---------------------------------------------------------------------------
extern "C" void kernel_launch(void* const* d_in, const int* in_sizes, int n_in,
                              void* d_out, int out_size, void* d_ws, size_t ws_size,
                              hipStream_t stream)
{
    const float* x     = (const float*)d_in[0];
    const float* W1    = (const float*)d_in[1];
    const float* b1    = (const float*)d_in[2];
    const float* W2    = (const float*)d_in[3];
    const float* b2    = (const float*)d_in[4];
    const float* Wt    = (const float*)d_in[5];
    const float* bt    = (const float*)d_in[6];
    const float* Wa    = (const float*)d_in[7];
    const float* ba    = (const float*)d_in[8];
    const float* Wr    = (const float*)d_in[9];
    const float* br    = (const float*)d_in[10];
    const float* gamma = (const float*)d_in[11];
    const float* beta  = (const float*)d_in[12];
    float* out = (float*)d_out;

    char* ws = (char*)d_ws;
    float*          c1    = (float*)(ws);                         // 512 KB
    float*          c2P   = (float*)(ws + (512 << 10));           // 512 KB
    unsigned short* wpack = (unsigned short*)(ws + (1024 << 10)); // 32 KB
    float*          Sp    = (float*)(ws + (1056 << 10));          // 2 MB

    prep_kernel<<<512, 256, 0, stream>>>(x, W1, b1, c1, c2P, wpack);
    pair_kernel<<<1024, 256, 0, stream>>>(x, c1, c2P, wpack, Sp);
    finish_kernel<<<BB / 2, 256, 0, stream>>>(Sp, W2, b2, x, Wt, bt,
                                              Wa, ba, Wr, br, gamma, beta, out);
}